// Round 17
// baseline (456.011 us; speedup 1.0000x reference)
//
#include <hip/hip_runtime.h>
#include <hip/hip_bf16.h>
#include <math.h>
#include <string.h>

#define B_ 128
#define L_ 128
#define N_ 6
#define FA_ 39
#define FB_ 10
#define D_ 200
#define MB_ 256
#define R_ 3
#define T_ 2
#define NEGV -9e8f
#define BL_ (B_*L_)        // 16384
#define G3D_ (3*D_)        // 600
#define FP32TAG 0x3F800000u
#define KP 416             // padded K for gate GEMM
#define NP 896             // padded N for gate GEMM (7*128); packed n = j*4+c
#define KC 224             // padded K for ctx GEMM (7*32)
#define NC 256             // padded N for ctx GEMM

typedef __hip_bfloat16 bf16;
typedef __attribute__((ext_vector_type(8))) short short8;
typedef __attribute__((ext_vector_type(4))) float f32x4;

__device__ __forceinline__ float b2f(const bf16 x){ return __bfloat162float(x); }
__device__ __forceinline__ unsigned short f2b(float v){ bf16 t = __float2bfloat16(v); return *reinterpret_cast<unsigned short*>(&t); }
__device__ __forceinline__ float bu2f(unsigned short u){ unsigned x = ((unsigned)u)<<16; float f; memcpy(&f,&x,4); return f; }
__device__ __forceinline__ float lreluf(float x){ return x>=0.f ? x : 0.01f*x; }
__device__ __forceinline__ float eluf(float x){ return x>0.f ? x : expm1f(x); }
__device__ __forceinline__ float sigmf(float x){ return 1.f/(1.f+expf(-x)); }

#define NSEG 14
struct CvtArgs { const void* src[NSEG]; int ofs[NSEG+1]; };

#define PREPB_N (R_*NP*KP)     // 1118208
#define PREPW_N (R_*NC*KC)     // 172032
#define PREPM_N (D_*G3D_)      // 120000
#define PREPT_N 40000          // Wmt16
#define PREPE_N 80000          // Wme16
#define CONV_N 23989
#define XHPAD2_N (2*BL_*16)    // 524288 (both XH buffers)
#define CURPAD_N (BL_*24)      // 393216
#define ZB_N (3*BL_)           // 49152 (s1, tb, curdot)
#define AROWS (BL_ + B_*MB_)   // 49152
#define A_N (AROWS*64)         // 3145728
#define BI_N (448*64)          // 28672

struct PrepArgs {
    CvtArgs cvt;
    const void *Wih, *Whh, *Watt, *mWih, *mWhh, *Wmt, *Wme;
    const void *bond, *Wnei, *atom, *Watom;
    float* conv;
    unsigned short *B2t, *WatT, *mTi, *mTh, *Wmt16, *Wme16, *XHa, *XHb, *A16, *Bi16, *cur16;
    float* zbase;            // s1, tb, curdot contiguous
    const unsigned* amtag;
    int ew_total;
};

__device__ __forceinline__ float ldd(const void* p, size_t i, bool f32){
    return f32 ? ((const float*)p)[i] : b2f(((const bf16*)p)[i]);
}

// prologue elementwise: convert + weight repacks (B2 packed n=j*4+c) + pads + zero bufs + A/Bi
__global__ void __launch_bounds__(256) k_prep(PrepArgs A){
    bool f32 = (*A.amtag == FP32TAG);
    int i = blockIdx.x*256 + (int)threadIdx.x;
    if (i >= A.ew_total) return;
    if (i < CONV_N){
        int s = 0;
        while (i >= A.cvt.ofs[s+1]) s++;
        A.conv[i] = ldd(A.cvt.src[s], i - A.cvt.ofs[s], f32);
        return;
    }
    int i2 = i - CONV_N;
    if (i2 < PREPB_N){
        int kk = i2 % KP;
        int rest = i2 / KP;
        int n = rest % NP;
        int r = rest / NP;
        int j = n >> 2, c = n & 3;
        float v = 0.f;
        if (j < 200){
            if (c == 0){
                if (kk < 200) v = ldd(A.Wih, ((size_t)(r*G3D_ + j))*D_ + kk, f32);
                else if (kk < 400) v = ldd(A.Whh, ((size_t)(r*G3D_ + j))*D_ + (kk-200), f32);
            } else if (c == 1){
                if (kk < 200) v = ldd(A.Wih, ((size_t)(r*G3D_ + 200 + j))*D_ + kk, f32);
                else if (kk < 400) v = ldd(A.Whh, ((size_t)(r*G3D_ + 200 + j))*D_ + (kk-200), f32);
            } else if (c == 2){
                if (kk < 200) v = ldd(A.Wih, ((size_t)(r*G3D_ + 400 + j))*D_ + kk, f32);
            } else {
                if (kk >= 200 && kk < 400) v = ldd(A.Whh, ((size_t)(r*G3D_ + 400 + j))*D_ + (kk-200), f32);
            }
        }
        A.B2t[i2] = f2b(v);
        return;
    }
    int i3 = i2 - PREPB_N;
    if (i3 < PREPW_N){
        int kk = i3 % KC;
        int rest = i3 / KC;
        int n = rest % NC;
        int r = rest / NC;
        float v = 0.f;
        if (kk < 200 && n < 200) v = ldd(A.Watt, ((size_t)r*D_ + kk)*D_ + n, f32);
        A.WatT[i3] = f2b(v);
        return;
    }
    int i4 = i3 - PREPW_N;
    if (i4 < PREPM_N){
        int j = i4 % G3D_, k = i4 / G3D_;
        size_t si = (size_t)j*D_ + k;
        A.mTi[i4] = f2b(ldd(A.mWih, si, f32));
        A.mTh[i4] = f2b(ldd(A.mWhh, si, f32));
        return;
    }
    int i5 = i4 - PREPM_N;
    if (i5 < PREPT_N){ A.Wmt16[i5] = f2b(ldd(A.Wmt, i5, f32)); return; }
    int i6 = i5 - PREPT_N;
    if (i6 < PREPE_N){ A.Wme16[i6] = f2b(ldd(A.Wme, i6, f32)); return; }
    int i7 = i6 - PREPE_N;
    if (i7 < XHPAD2_N){
        int buf = i7 >> 18;                    // BL_*16 = 2^18
        int loc = i7 & (BL_*16 - 1);
        int al = loc >> 4, p = loc & 15;
        unsigned short* X = buf ? A.XHb : A.XHa;
        X[(size_t)al*KP + 400 + p] = 0;
        return;
    }
    int i8 = i7 - XHPAD2_N;
    if (i8 < CURPAD_N){
        int al = i8 / 24, p = i8 - al*24;
        A.cur16[(size_t)al*KC + 200 + p] = 0;
        return;
    }
    int i9 = i8 - CURPAD_N;
    if (i9 < ZB_N){ A.zbase[i9] = 0.f; return; }
    int i10 = i9 - ZB_N;
    if (i10 < A_N){
        int row = i10 >> 6, k = i10 & 63;
        float v = 0.f;
        if (row < BL_){
            if (k < FA_) v = ldd(A.atom, (size_t)row*FA_ + k, f32);
        } else {
            int rb = row - BL_;
            if (k >= FA_ && k < FA_+FB_) v = ldd(A.bond, (size_t)rb*FB_ + (k-FA_), f32);
        }
        A.A16[i10] = f2b(v);
        return;
    }
    int i11 = i10 - A_N;
    if (i11 < BI_N){
        int n = i11 >> 6, k = i11 & 63;
        float v = 0.f;
        if (n < 200){
            if (k < FA_) v = ldd(A.Watom, (size_t)k*D_ + n, f32);
        } else if (n < 400){
            if (k < FA_+FB_) v = ldd(A.Wnei, (size_t)k*D_ + (n-200), f32);
        }
        A.Bi16[i11] = f2b(v);
    }
}

// MFMA init GEMM: atom rows -> XHa h-half (lrelu+b_atom) + P16 (+b_nei); bond rows -> Q16.
__global__ void __launch_bounds__(256) k_initmm(const unsigned short* __restrict__ A16,
        const unsigned short* __restrict__ Bi16,
        const void* __restrict__ batom, const void* __restrict__ bnei,
        unsigned short* __restrict__ XH, unsigned short* __restrict__ P16,
        unsigned short* __restrict__ Q16, const unsigned* __restrict__ amtag){
    __shared__ unsigned short As[128][40];
    __shared__ unsigned short Bs[64][40];
    bool f32 = (*amtag == FP32TAG);
    int tid = threadIdx.x;
    int mt = (int)blockIdx.x / 7, nt = (int)blockIdx.x % 7;
    int m0 = mt*128, n0 = nt*64;
    if (m0 >= BL_ && n0 + 64 <= 200) return;
    int lane = tid & 63, wv = tid >> 6;
    int quad = lane >> 4, lm = lane & 15;
    f32x4 acc[2][4];
    #pragma unroll
    for (int a=0;a<2;a++)
        #pragma unroll
        for (int b=0;b<4;b++) acc[a][b] = (f32x4){0.f,0.f,0.f,0.f};
    for (int ks = 0; ks < 2; ks++){
        int r0_ = tid >> 2, c0 = (tid & 3) * 8;
        int r1_ = (tid + 256) >> 2, c1 = ((tid + 256) & 3) * 8;
        uint4 a0 = *(const uint4*)&A16[(size_t)(m0 + r0_)*64 + ks*32 + c0];
        uint4 a1 = *(const uint4*)&A16[(size_t)(m0 + r1_)*64 + ks*32 + c1];
        uint4 b0 = *(const uint4*)&Bi16[(size_t)(n0 + (tid >> 2))*64 + ks*32 + (tid & 3)*8];
        __syncthreads();
        *(uint4*)&As[r0_][c0] = a0;
        *(uint4*)&As[r1_][c1] = a1;
        *(uint4*)&Bs[tid >> 2][(tid & 3)*8] = b0;
        __syncthreads();
        short8 av0 = *(const short8*)&As[wv*32 + lm][quad*8];
        short8 av1 = *(const short8*)&As[wv*32 + 16 + lm][quad*8];
        #pragma unroll
        for (int ns=0; ns<4; ns++){
            short8 bv = *(const short8*)&Bs[ns*16 + lm][quad*8];
            acc[0][ns] = __builtin_amdgcn_mfma_f32_16x16x32_bf16(av0, bv, acc[0][ns], 0,0,0);
            acc[1][ns] = __builtin_amdgcn_mfma_f32_16x16x32_bf16(av1, bv, acc[1][ns], 0,0,0);
        }
    }
    #pragma unroll
    for (int ms=0; ms<2; ms++)
      #pragma unroll
      for (int ns=0; ns<4; ns++){
        int n = n0 + ns*16 + lm;
        #pragma unroll
        for (int i=0;i<4;i++){
            int row = m0 + wv*32 + ms*16 + quad*4 + i;
            float v = acc[ms][ns][i];
            if (row < BL_){
                if (n < 200){
                    XH[(size_t)row*KP + 200 + n] = f2b(lreluf(v + ldd(batom, n, f32)));
                } else if (n < 400){
                    P16[(size_t)row*D_ + (n-200)] = f2b(v + ldd(bnei, n-200, f32));
                }
            } else if (n >= 200 && n < 400){
                Q16[(size_t)(row-BL_)*D_ + (n-200)] = f2b(v);
            }
        }
      }
}

// attention: softmax + weighted neighbor sum -> bf16 wnei. XCD swizzle mol=bid&127.
__global__ void __launch_bounds__(256) k_attn(
        const unsigned short* __restrict__ cur16, const unsigned short* __restrict__ XH,
        const float* __restrict__ s1, const float* __restrict__ tb,
        const int* __restrict__ adl, const int* __restrict__ bdl,
        const unsigned short* __restrict__ P16, const unsigned short* __restrict__ Q16,
        const float* __restrict__ W_align, const float* __restrict__ b_align, int r,
        unsigned short* __restrict__ wnei, float* __restrict__ wsum){
    int bid = blockIdx.x;
    int mol = bid & (B_-1), chunk = bid >> 7;
    int wv = threadIdx.x >> 6, lane = threadIdx.x & 63;
    int al = mol*L_ + chunk*4 + wv;
    __shared__ float s_nei[4][N_][D_];

    int idxn[N_]; bool pad[N_];
    for (int n=0;n<N_;n++){ idxn[n] = adl[al*N_ + n]; pad[n] = (idxn[n] == L_-1); }

    float s2[N_];
    float s1v;
    if (r == 0){
        for (int j = lane; j < N_*D_; j += 64){
            int n = j / D_, d = j - n*D_;
            int bd = bdl[al*N_ + n];
            float acc = bu2f(P16[((size_t)mol*L_ + idxn[n])*D_ + d])
                      + bu2f(Q16[((size_t)mol*MB_ + bd)*D_ + d]);
            s_nei[wv][n][d] = lreluf(acc);
        }
        const float* Wab = W_align + D_;
        for (int n=0;n<N_;n++){
            float acc = 0.f;
            for (int d=lane; d<D_; d+=64) acc += s_nei[wv][n][d] * Wab[d];
            for (int o=32;o>0;o>>=1) acc += __shfl_xor(acc,o);
            s2[n] = acc;
        }
        float a1 = 0.f;
        for (int d=lane; d<D_; d+=64) a1 += bu2f(XH[(size_t)al*KP + 200 + d]) * W_align[d];
        for (int o=32;o>0;o>>=1) a1 += __shfl_xor(a1,o);
        s1v = a1;
    } else {
        float tmp = 0.f;
        if (lane < N_) tmp = tb[mol*L_ + idxn[lane]];
        for (int n=0;n<N_;n++) s2[n] = __shfl(tmp, n);
        s1v = s1[al];
    }

    float bav = b_align[r];
    float a[N_]; float mx = -1e30f;
    for (int n=0;n<N_;n++){
        float v = lreluf(s1v + s2[n] + bav);
        if (pad[n]) v += NEGV;
        a[n] = v; mx = fmaxf(mx, v);
    }
    float w[N_]; float se = 0.f;
    for (int n=0;n<N_;n++){ float e = expf(a[n]-mx); w[n]=e; se += e; }
    float inv = 1.f/se; float wsv = 0.f;
    for (int n=0;n<N_;n++){ w[n] = pad[n] ? 0.f : w[n]*inv; wsv += w[n]; }

    if (r == 0){
        for (int d=lane; d<D_; d+=64){
            float acc = 0.f;
            #pragma unroll
            for (int n=0;n<N_;n++) acc += w[n] * s_nei[wv][n][d];
            wnei[(size_t)al*KC + d] = f2b(acc);
        }
    } else {
        for (int d=lane; d<D_; d+=64){
            float acc = 0.f;
            #pragma unroll
            for (int n=0;n<N_;n++) acc += w[n] * bu2f(cur16[((size_t)mol*L_ + idxn[n])*KC + d]);
            wnei[(size_t)al*KC + d] = f2b(acc);
        }
    }
    if (lane < 24) wnei[(size_t)al*KC + 200 + lane] = 0;
    if (lane==0) wsum[al] = wsv;
}

// MFMA ctx GEMM: elu(wnei @ WatT[r]^T + wsum*bias) -> XH_r x-half. Also zeroes s1/tb (n0==0).
__global__ void __launch_bounds__(256) k_ctxmfma(const unsigned short* __restrict__ Wn,
        const float* __restrict__ wsum, const unsigned short* __restrict__ WatT,
        const float* __restrict__ bias, int r, unsigned short* __restrict__ XH,
        float* __restrict__ s1z, float* __restrict__ tbz){
    __shared__ unsigned short As[128][40];
    __shared__ unsigned short Bs[64][40];
    int tid = threadIdx.x;
    int m0 = ((int)blockIdx.x & 127) * 128;
    int n0 = ((int)blockIdx.x >> 7) * 64;
    if (n0 == 0){
        for (int idx = tid; idx < 128; idx += 256){ s1z[m0+idx] = 0.f; tbz[m0+idx] = 0.f; }
    }
    const unsigned short* Bt = WatT + (size_t)r*NC*KC;
    int lane = tid & 63, wv = tid >> 6;
    int quad = lane >> 4, lm = lane & 15;
    f32x4 acc[2][4];
    #pragma unroll
    for (int a=0;a<2;a++)
        #pragma unroll
        for (int b=0;b<4;b++) acc[a][b] = (f32x4){0.f,0.f,0.f,0.f};
    for (int ks = 0; ks < 7; ks++){
        int r0_ = tid >> 2, c0 = (tid & 3) * 8;
        int r1_ = (tid + 256) >> 2, c1 = ((tid + 256) & 3) * 8;
        uint4 a0 = *(const uint4*)&Wn[(size_t)(m0 + r0_)*KC + ks*32 + c0];
        uint4 a1 = *(const uint4*)&Wn[(size_t)(m0 + r1_)*KC + ks*32 + c1];
        uint4 b0 = *(const uint4*)&Bt[(size_t)(n0 + (tid >> 2))*KC + ks*32 + (tid & 3)*8];
        __syncthreads();
        *(uint4*)&As[r0_][c0] = a0;
        *(uint4*)&As[r1_][c1] = a1;
        *(uint4*)&Bs[tid >> 2][(tid & 3)*8] = b0;
        __syncthreads();
        short8 av0 = *(const short8*)&As[wv*32 + lm][quad*8];
        short8 av1 = *(const short8*)&As[wv*32 + 16 + lm][quad*8];
        #pragma unroll
        for (int ns=0; ns<4; ns++){
            short8 bv = *(const short8*)&Bs[ns*16 + lm][quad*8];
            acc[0][ns] = __builtin_amdgcn_mfma_f32_16x16x32_bf16(av0, bv, acc[0][ns], 0,0,0);
            acc[1][ns] = __builtin_amdgcn_mfma_f32_16x16x32_bf16(av1, bv, acc[1][ns], 0,0,0);
        }
    }
    #pragma unroll
    for (int ms=0; ms<2; ms++)
      #pragma unroll
      for (int ns=0; ns<4; ns++){
        int n = n0 + ns*16 + lm;
        if (n < 200){
            float bv = bias[r*D_ + n];
            #pragma unroll
            for (int i=0;i<4;i++){
                int row = m0 + wv*32 + ms*16 + quad*4 + i;
                float v = acc[ms][ns][i] + wsum[row]*bv;
                XH[(size_t)row*KP + n] = f2b(eluf(v));
            }
        }
      }
}

// fused gate GEMM + GRU combine. B2 packed n=j*4+c. Reads XHr ([x|h]); writes new h to XHn
// h-half, cur for round r+1 to cur16; accumulates s1/tb (r<2) or curdot (r==2) via atomics.
__global__ void __launch_bounds__(256) k_gg(const unsigned short* __restrict__ XHr,
        const unsigned short* __restrict__ B2t, unsigned short* __restrict__ XHn,
        unsigned short* __restrict__ cur16,
        const float* __restrict__ bih, const float* __restrict__ bhh,
        const float* __restrict__ W_align, const float* __restrict__ Wma, int r,
        float* __restrict__ s1, float* __restrict__ tb, float* __restrict__ curdot){
    __shared__ unsigned short As[128][40];
    __shared__ unsigned short Bs[128][40];
    __shared__ unsigned short Cs[128][130];
    __shared__ unsigned short hs[128][32];
    int tid = threadIdx.x;
    int m0 = ((int)blockIdx.x & 127) * 128;
    int nt = (int)blockIdx.x >> 7;
    int n0 = nt * 128;
    int jbase = nt * 32;
    const unsigned short* Bt = B2t + (size_t)r*NP*KP;
    int lane = tid & 63, wv = tid >> 6;
    int quad = lane >> 4, lm = lane & 15;
    // stage old h tile (rows m0.., cols jbase..jbase+31)
    for (int idx = tid; idx < 128*4; idx += 256){
        int row = idx >> 2, ch = idx & 3;
        if (200 + jbase + ch*8 + 8 <= KP)
            *(uint4*)&hs[row][ch*8] = *(const uint4*)&XHr[(size_t)(m0+row)*KP + 200 + jbase + ch*8];
    }
    f32x4 acc[2][8];
    #pragma unroll
    for (int a=0;a<2;a++)
        #pragma unroll
        for (int b=0;b<8;b++) acc[a][b] = (f32x4){0.f,0.f,0.f,0.f};
    for (int ks = 0; ks < 13; ks++){
        int r0_ = tid >> 2, c0 = (tid & 3) * 8;
        int r1_ = (tid + 256) >> 2, c1 = ((tid + 256) & 3) * 8;
        uint4 a0 = *(const uint4*)&XHr[(size_t)(m0 + r0_)*KP + ks*32 + c0];
        uint4 a1 = *(const uint4*)&XHr[(size_t)(m0 + r1_)*KP + ks*32 + c1];
        uint4 b0 = *(const uint4*)&Bt[(size_t)(n0 + r0_)*KP + ks*32 + c0];
        uint4 b1 = *(const uint4*)&Bt[(size_t)(n0 + r1_)*KP + ks*32 + c1];
        __syncthreads();
        *(uint4*)&As[r0_][c0] = a0;
        *(uint4*)&As[r1_][c1] = a1;
        *(uint4*)&Bs[r0_][c0] = b0;
        *(uint4*)&Bs[r1_][c1] = b1;
        __syncthreads();
        short8 av0 = *(const short8*)&As[wv*32 + lm][quad*8];
        short8 av1 = *(const short8*)&As[wv*32 + 16 + lm][quad*8];
        #pragma unroll
        for (int ns=0; ns<8; ns++){
            short8 bv = *(const short8*)&Bs[ns*16 + lm][quad*8];
            acc[0][ns] = __builtin_amdgcn_mfma_f32_16x16x32_bf16(av0, bv, acc[0][ns], 0,0,0);
            acc[1][ns] = __builtin_amdgcn_mfma_f32_16x16x32_bf16(av1, bv, acc[1][ns], 0,0,0);
        }
    }
    // fragments -> LDS C tile
    #pragma unroll
    for (int ms=0; ms<2; ms++)
      #pragma unroll
      for (int ns=0; ns<8; ns++)
        #pragma unroll
        for (int i=0;i<4;i++)
            Cs[wv*32 + ms*16 + quad*4 + i][ns*16 + lm] = f2b(acc[ms][ns][i]);
    __syncthreads();
    // GRU combine: lanes jl=tid&31 cover j, rows iterate
    int jl = tid & 31;
    int rowb = tid >> 5;            // 0..7
    int j = jbase + jl;
    bool jv = (j < 200);
    bool last = (r == R_-1);
    const float* bi = bih + r*G3D_;
    const float* bh = bhh + r*G3D_;
    float bir=0,biz=0,bin=0,bhr=0,bhz=0,bhn=0,wj=0,wj2=0;
    if (jv){
        bir = bi[j]; biz = bi[D_+j]; bin = bi[2*D_+j];
        bhr = bh[j]; bhz = bh[D_+j]; bhn = bh[2*D_+j];
        if (!last){ const float* Wa = W_align + (r+1)*2*D_; wj = Wa[j]; wj2 = Wa[D_+j]; }
        else wj2 = Wma[D_+j];
    }
    for (int it=0; it<16; it++){
        int row = rowb + 8*it;
        int rowG = m0 + row;
        float s1p = 0.f, tbp = 0.f;
        if (jv){
            float rsum = bu2f(Cs[row][jl*4+0]);
            float zsum = bu2f(Cs[row][jl*4+1]);
            float gin  = bu2f(Cs[row][jl*4+2]);
            float ghn  = bu2f(Cs[row][jl*4+3]);
            float rr = sigmf(rsum + bir + bhr);
            float zz = sigmf(zsum + biz + bhz);
            float nn = tanhf(gin + bin + rr*(ghn + bhn));
            float hold = bu2f(hs[row][jl]);
            float hn = (1.f-zz)*nn + zz*hold;
            XHn[(size_t)rowG*KP + 200 + j] = f2b(hn);
            float cv = fmaxf(hn, 0.f);
            cur16[(size_t)rowG*KC + j] = f2b(cv);
            if (!last){ s1p = cv*wj; tbp = cv*wj2; }
            else s1p = cv*wj2;
        }
        for (int o=16;o>0;o>>=1){ s1p += __shfl_xor(s1p,o); tbp += __shfl_xor(tbp,o); }
        if (jl == 0){
            if (!last){ atomicAdd(&s1[rowG], s1p); atomicAdd(&tb[rowG], tbp); }
            else atomicAdd(&curdot[rowG], s1p);
        }
    }
}

__device__ __forceinline__ float brSum(float v, float* s_red){
    for (int o=32;o>0;o>>=1) v += __shfl_xor(v,o);
    int lane = threadIdx.x & 63, wid = threadIdx.x >> 6;
    __syncthreads();
    if (lane==0) s_red[wid] = v;
    __syncthreads();
    float r = 0.f;
    int nw = blockDim.x >> 6;
    for (int i=0;i<nw;i++) r += s_red[i];
    return r;
}

__device__ __forceinline__ float brMax(float v, float* s_red){
    for (int o=32;o>0;o>>=1) v = fmaxf(v, __shfl_xor(v,o));
    int lane = threadIdx.x & 63, wid = threadIdx.x >> 6;
    __syncthreads();
    if (lane==0) s_red[wid] = v;
    __syncthreads();
    float r = s_red[0];
    int nw = blockDim.x >> 6;
    for (int i=1;i<nw;i++) r = fmaxf(r, s_red[i]);
    return r;
}

// molecule phase, 512 threads; cur16 tile in LDS; bf16 weights; gates GEMV unroll-4.
__global__ void __launch_bounds__(512) k_mol(const unsigned short* __restrict__ cur16,
    const float* __restrict__ curdot, const float* __restrict__ atom_mask,
    const float* __restrict__ Wma, const float* __restrict__ bma,
    const unsigned short* __restrict__ Wmt16, const float* __restrict__ bmt,
    const unsigned short* __restrict__ mTi, const unsigned short* __restrict__ mTh,
    const float* __restrict__ mbih, const float* __restrict__ mbhh,
    const unsigned short* __restrict__ Wme16, const float* __restrict__ bme,
    const float* __restrict__ Wout, const float* __restrict__ bout,
    void* __restrict__ out, const unsigned* __restrict__ amtag){
    int b = blockIdx.x, tid = threadIdx.x;
    int dq = tid & 255, cq = tid >> 8;
    __shared__ unsigned short s_cur[L_*KC];
    __shared__ float s_am[L_], s_neg[L_], s_cd[L_], s_w[L_];
    __shared__ float s_mf[D_], s_act[D_], s_wc[D_], s_ctx[D_];
    __shared__ float s_gi[G3D_], s_gh[G3D_];
    __shared__ float s_part[2][256];
    __shared__ float s_red[8];
    const uint4* src = (const uint4*)(cur16 + (size_t)b*L_*KC);
    for (int i = tid; i < L_*KC/8; i += 512) ((uint4*)s_cur)[i] = src[i];
    if (tid < L_){
        float am = atom_mask[b*L_ + tid];
        s_am[tid] = am;
        s_neg[tid] = (am == 0.f) ? NEGV : 0.f;
        s_cd[tid] = curdot[b*L_ + tid];
    }
    __syncthreads();
    {
        float a0 = 0.f, a1 = 0.f;
        if (dq < D_)
            for (int l=cq*64; l<cq*64+64; l+=2){
                a0 += bu2f(s_cur[l*KC + dq]) * s_am[l];
                a1 += bu2f(s_cur[(l+1)*KC + dq]) * s_am[l+1];
            }
        s_part[cq][dq] = a0 + a1;
        __syncthreads();
        if (tid < D_){
            float v = s_part[0][tid] + s_part[1][tid];
            s_mf[tid] = v; s_act[tid] = fmaxf(v, 0.f);
        }
        __syncthreads();
    }
    float bma0 = bma[0];
    for (int t=0;t<T_;t++){
        float p = (tid < D_) ? s_act[tid] * Wma[tid] : 0.f;
        float s1v = brSum(p, s_red);
        float sc = (tid < L_) ? (lreluf(s1v + s_cd[tid] + bma0) + s_neg[tid]) : -1e30f;
        float mx = brMax(sc, s_red);
        float e = (tid < L_) ? expf(sc - mx) : 0.f;
        float se = brSum(e, s_red);
        float wv_ = (tid < L_) ? e/se*s_am[tid] : 0.f;
        if (tid < L_) s_w[tid] = wv_;
        float wsm = brSum(wv_, s_red);
        __syncthreads();
        {
            float a0 = 0.f, a1 = 0.f;
            if (dq < D_)
                for (int l=cq*64; l<cq*64+64; l+=2){
                    a0 += s_w[l] * bu2f(s_cur[l*KC + dq]);
                    a1 += s_w[l+1] * bu2f(s_cur[(l+1)*KC + dq]);
                }
            s_part[cq][dq] = a0 + a1;
            __syncthreads();
            if (tid < D_) s_wc[tid] = s_part[0][tid] + s_part[1][tid];
            __syncthreads();
        }
        {
            float a0 = 0.f, a1 = 0.f;
            if (dq < D_)
                for (int k=cq*100; k<cq*100+100; k+=2){
                    a0 += s_wc[k] * bu2f(Wmt16[(size_t)k*D_ + dq]);
                    a1 += s_wc[k+1] * bu2f(Wmt16[(size_t)(k+1)*D_ + dq]);
                }
            s_part[cq][dq] = a0 + a1;
            __syncthreads();
            if (tid < D_)
                s_ctx[tid] = eluf(s_part[0][tid] + s_part[1][tid] + wsm * bmt[tid]);
            __syncthreads();
        }
        for (int j=tid; j<G3D_; j+=512){
            float ai0=0.f, ai1=0.f, ai2=0.f, ai3=0.f;
            float ah0=0.f, ah1=0.f, ah2=0.f, ah3=0.f;
            for (int k=0;k<D_;k+=4){
                ai0 += s_ctx[k]   * bu2f(mTi[(size_t)k*G3D_ + j]);
                ai1 += s_ctx[k+1] * bu2f(mTi[(size_t)(k+1)*G3D_ + j]);
                ai2 += s_ctx[k+2] * bu2f(mTi[(size_t)(k+2)*G3D_ + j]);
                ai3 += s_ctx[k+3] * bu2f(mTi[(size_t)(k+3)*G3D_ + j]);
                ah0 += s_mf[k]    * bu2f(mTh[(size_t)k*G3D_ + j]);
                ah1 += s_mf[k+1]  * bu2f(mTh[(size_t)(k+1)*G3D_ + j]);
                ah2 += s_mf[k+2]  * bu2f(mTh[(size_t)(k+2)*G3D_ + j]);
                ah3 += s_mf[k+3]  * bu2f(mTh[(size_t)(k+3)*G3D_ + j]);
            }
            s_gi[j] = (ai0+ai1)+(ai2+ai3); s_gh[j] = (ah0+ah1)+(ah2+ah3);
        }
        __syncthreads();
        if (tid < D_){
            int d = tid;
            float rr = sigmf(s_gi[d] + mbih[d] + s_gh[d] + mbhh[d]);
            float zz = sigmf(s_gi[D_+d] + mbih[D_+d] + s_gh[D_+d] + mbhh[D_+d]);
            float nn = tanhf(s_gi[2*D_+d] + mbih[2*D_+d] + rr*(s_gh[2*D_+d] + mbhh[2*D_+d]));
            float nm = (1.f-zz)*nn + zz*s_mf[d];
            s_mf[d] = nm; s_act[d] = fmaxf(nm, 0.f);
        }
        __syncthreads();
    }
    const float dd = (float)(R_ - 2);
    {
        float a0 = 0.f, a1 = 0.f;
        if (dq < D_)
            for (int k=cq*100; k<cq*100+100; k+=2){
                float mf0 = s_mf[k], mf1 = s_mf[k+1];
                a0 += mf0 * bu2f(Wme16[(size_t)k*D_ + dq])
                    + (mf0 + dd) * bu2f(Wme16[(size_t)(D_+k)*D_ + dq]);
                a1 += mf1 * bu2f(Wme16[(size_t)(k+1)*D_ + dq])
                    + (mf1 + dd) * bu2f(Wme16[(size_t)(D_+k+1)*D_ + dq]);
            }
        s_part[cq][dq] = a0 + a1;
        __syncthreads();
        float p = 0.f;
        if (tid < D_)
            p = (s_part[0][tid] + s_part[1][tid] + bme[tid]) * Wout[tid];
        float o = brSum(p, s_red);
        if (tid==0){
            o += bout[0];
            if (*amtag == FP32TAG) ((float*)out)[b] = o;
            else ((bf16*)out)[b] = __float2bfloat16(o);
        }
    }
}

extern "C" void kernel_launch(void* const* d_in, const int* in_sizes, int n_in,
                              void* d_out, int out_size, void* d_ws, size_t ws_size,
                              hipStream_t stream) {
    const int* adl = (const int*)d_in[2];
    const int* bdl = (const int*)d_in[3];
    const unsigned* amtag = (const unsigned*)d_in[4];

    static const int srcidx[NSEG] = {4,9,10,12,15,16,17,18,20,23,24,26,27,28};
    static const int segsz[NSEG]  = {16384,1200,3,600,1800,1800,400,1,200,600,600,200,200,1};
    CvtArgs ca;
    int ofs[NSEG+1]; ofs[0] = 0;
    for (int i=0;i<NSEG;i++){ ca.src[i] = d_in[srcidx[i]]; ca.ofs[i] = ofs[i]; ofs[i+1] = ofs[i] + segsz[i]; }
    ca.ofs[NSEG] = ofs[NSEG];   // 23989

    // ws layout. ~66 MB total.
    float* ws   = (float*)d_ws;
    float* conv = ws;                                            // 24000 fl
    unsigned short* XHa   = (unsigned short*)(conv + 24000);     // BL_*KP sh
    unsigned short* XHb   = XHa + (size_t)BL_*KP;                // BL_*KP sh
    unsigned short* B2t   = XHb + (size_t)BL_*KP;                // PREPB_N sh
    unsigned short* WatT  = B2t + PREPB_N;                       // PREPW_N sh
    unsigned short* mTi   = WatT + PREPW_N;                      // PREPM_N sh
    unsigned short* mTh   = mTi + PREPM_N;                       // PREPM_N sh
    unsigned short* Wmt16 = mTh + PREPM_N;                       // PREPT_N sh
    unsigned short* Wme16 = Wmt16 + PREPT_N;                     // PREPE_N sh
    unsigned short* Bi16  = Wme16 + PREPE_N;                     // BI_N sh
    unsigned short* cur16 = Bi16 + BI_N;                         // BL_*KC sh
    unsigned short* creg  = cur16 + (size_t)BL_*KC;              // overlay region
    unsigned short* A16  = creg;                                 // AROWS*64 sh (prologue)
    unsigned short* wnei = creg;                                 // BL_*KC sh (rounds)
    unsigned short* Q16  = creg + (size_t)BL_*KC;                // B_*MB_*D_ sh
    unsigned short* P16  = Q16 + (size_t)B_*MB_*D_;              // BL_*D_ sh
    float* s1     = (float*)(P16 + (size_t)BL_*D_);
    float* tb     = s1 + BL_;
    float* curdot = tb + BL_;
    float* wsum   = curdot + BL_;

    const float* c_amask = conv + ofs[0];
    const float* c_Walign= conv + ofs[1];
    const float* c_balign= conv + ofs[2];
    const float* c_batt  = conv + ofs[3];
    const float* c_bih   = conv + ofs[4];
    const float* c_bhh   = conv + ofs[5];
    const float* c_Wma   = conv + ofs[6];
    const float* c_bma   = conv + ofs[7];
    const float* c_bmt   = conv + ofs[8];
    const float* c_mbih  = conv + ofs[9];
    const float* c_mbhh  = conv + ofs[10];
    const float* c_bme   = conv + ofs[11];
    const float* c_Wout  = conv + ofs[12];
    const float* c_bout  = conv + ofs[13];

    PrepArgs A;
    A.cvt = ca;
    A.Wih = d_in[13]; A.Whh = d_in[14]; A.Watt = d_in[11];
    A.mWih = d_in[21]; A.mWhh = d_in[22]; A.Wmt = d_in[19]; A.Wme = d_in[25];
    A.bond = d_in[1]; A.Wnei = d_in[7]; A.atom = d_in[0]; A.Watom = d_in[5];
    A.conv = conv;
    A.B2t = B2t; A.WatT = WatT; A.mTi = mTi; A.mTh = mTh;
    A.Wmt16 = Wmt16; A.Wme16 = Wme16; A.XHa = XHa; A.XHb = XHb;
    A.A16 = A16; A.Bi16 = Bi16; A.cur16 = cur16;
    A.zbase = s1;                      // zeroes s1, tb, curdot
    A.amtag = amtag;
    A.ew_total = CONV_N + PREPB_N + PREPW_N + PREPM_N + PREPT_N + PREPE_N
               + XHPAD2_N + CURPAD_N + ZB_N + A_N + BI_N;

    k_prep<<<(A.ew_total + 255)/256, 256, 0, stream>>>(A);
    k_initmm<<<(AROWS/128)*7, 256, 0, stream>>>(A16, Bi16, d_in[6], d_in[8],
                                                XHa, P16, Q16, amtag);

    for (int r=0; r<R_; r++){
        unsigned short* XH_r = (r & 1) ? XHb : XHa;
        unsigned short* XH_n = (r & 1) ? XHa : XHb;
        k_attn<<<BL_/4, 256, 0, stream>>>(cur16, XH_r, s1, tb, adl, bdl, P16, Q16,
                                          c_Walign, c_balign, r, wnei, wsum);
        k_ctxmfma<<<(BL_/128)*(NC/64), 256, 0, stream>>>(wnei, wsum, WatT, c_batt, r,
                                                         XH_r, s1, tb);
        k_gg<<<(BL_/128)*(NP/128), 256, 0, stream>>>(XH_r, B2t, XH_n, cur16,
                                                     c_bih, c_bhh, c_Walign, c_Wma, r,
                                                     s1, tb, curdot);
    }

    k_mol<<<B_, 512, 0, stream>>>(cur16, curdot, c_amask, c_Wma, c_bma, Wmt16, c_bmt,
                                  mTi, mTh, c_mbih, c_mbhh, Wme16, c_bme, c_Wout, c_bout,
                                  d_out, amtag);
}